// Round 6
// baseline (127.478 us; speedup 1.0000x reference)
//
#include <hip/hip_runtime.h>
#include <hip/hip_bf16.h>

#define B 64
#define F 2048
#define BN 16
#define BK 32
#define KSPLIT 2
#define KCHUNK (F / KSPLIT)   // 1024
#define NITER (KCHUNK / BK)   // 32
#define LDSW 40               // LDS row stride in shorts (80 B, 16B-aligned rows)

typedef __attribute__((ext_vector_type(8))) short bf16x8;
typedef __attribute__((ext_vector_type(4))) float f32x4;

#define PART_FLOATS (KSPLIT * 3 * B * F)  // 3.1 MB

#if __has_builtin(__builtin_amdgcn_exp2f)
#define EXP2(x) __builtin_amdgcn_exp2f(x)   // raw v_exp_f32, no denorm expansion
#else
#define EXP2(x) exp2f(x)
#endif

// RTZ hi/lo split of two floats, packed via v_perm. 3 ops/float.
__device__ __forceinline__ void split2(float f0, float f1, int& hi, int& lo) {
  union { float f; unsigned u; } a, b;
  a.f = f0; b.f = f1;
  union { unsigned u; float f; } ha, hb;
  ha.u = a.u & 0xFFFF0000u;
  hb.u = b.u & 0xFFFF0000u;
  union { float f; unsigned u; } la, lb;
  la.f = f0 - ha.f;
  lb.f = f1 - hb.f;
  hi = (int)__builtin_amdgcn_perm(b.u, a.u, 0x07060302u);
  lo = (int)__builtin_amdgcn_perm(lb.u, la.u, 0x07060302u);
}

// C[b,f] = sum_k x[b,k]*W[f,k], bf16 hi/lo split (3 MFMAs ~ fp32 accuracy).
// Split-K partials -> part[(kb*3+mat)*B*F]. LDS double-buffered, 1 barrier/iter.
// BN=16 x KSPLIT=2 -> 768 blocks = 3/CU (same concurrency as verified configs)
// with HALF the split-K partial traffic of round 5 (attn sums 2 partials).
// NO inter-block sync (round-2's fused handoff caused an L2-invalidate storm).
__global__ __launch_bounds__(256) void qkv_gemm_kernel(
    const float* __restrict__ x, const float* __restrict__ Wq,
    const float* __restrict__ Wk, const float* __restrict__ Wv,
    float* __restrict__ part) {
  __shared__ __align__(16) short xs_hi[2][B][LDSW];
  __shared__ __align__(16) short xs_lo[2][B][LDSW];
  __shared__ __align__(16) short ws_hi[2][BN][LDSW];
  __shared__ __align__(16) short ws_lo[2][BN][LDSW];

  const int tid  = threadIdx.x;
  const int f0   = blockIdx.x * BN;
  const int kb   = blockIdx.y;
  const int mat  = blockIdx.z;
  const float* W = (mat == 0) ? Wq : (mat == 1) ? Wk : Wv;

  const int lrow = tid >> 2;           // x staging row 0..63
  const int lc0  = (tid & 3) << 3;     // x staging col (shorts) 0,8,16,24
  const int wrow = tid >> 4;           // W staging row 0..15
  const int wc0  = (tid & 15) << 1;    // W staging col (shorts) 0,2,...,30

  const int wave = tid >> 6;
  const int lane = tid & 63;
  const int l15  = lane & 15;
  const int quad = lane >> 4;

  const float* xg = x + lrow * F + kb * KCHUNK + lc0;
  const float* wg = W + (f0 + wrow) * F + kb * KCHUNK + wc0;

  f32x4 acc = (f32x4){0.f, 0.f, 0.f, 0.f};

  float4 px[2][2];
  float2 pw[2];
  px[0][0] = *(const float4*)(xg);
  px[0][1] = *(const float4*)(xg + 4);
  pw[0]    = *(const float2*)(wg);

#pragma unroll
  for (int it = 0; it < NITER; ++it) {
    const int cur = it & 1, nxt = cur ^ 1;
    if (it + 1 < NITER) {  // prefetch next chunk into alternate regs
      const float* xp = xg + (it + 1) * BK;
      px[nxt][0] = *(const float4*)(xp);
      px[nxt][1] = *(const float4*)(xp + 4);
      pw[nxt]    = *(const float2*)(wg + (it + 1) * BK);
    }
    int4 xh, xl;
    int wh, wl;
    split2(px[cur][0].x, px[cur][0].y, xh.x, xl.x);
    split2(px[cur][0].z, px[cur][0].w, xh.y, xl.y);
    split2(px[cur][1].x, px[cur][1].y, xh.z, xl.z);
    split2(px[cur][1].z, px[cur][1].w, xh.w, xl.w);
    split2(pw[cur].x, pw[cur].y, wh, wl);
    *(int4*)&xs_hi[cur][lrow][lc0] = xh;
    *(int4*)&xs_lo[cur][lrow][lc0] = xl;
    *(int*)&ws_hi[cur][wrow][wc0] = wh;
    *(int*)&ws_lo[cur][wrow][wc0] = wl;
    __syncthreads();  // writes[cur] visible; prior iter's reads drained

    bf16x8 a_hi = *(const bf16x8*)&xs_hi[cur][(wave << 4) + l15][quad << 3];
    bf16x8 a_lo = *(const bf16x8*)&xs_lo[cur][(wave << 4) + l15][quad << 3];
    bf16x8 b_hi = *(const bf16x8*)&ws_hi[cur][l15][quad << 3];
    bf16x8 b_lo = *(const bf16x8*)&ws_lo[cur][l15][quad << 3];
    acc = __builtin_amdgcn_mfma_f32_16x16x32_bf16(a_hi, b_hi, acc, 0, 0, 0);
    acc = __builtin_amdgcn_mfma_f32_16x16x32_bf16(a_hi, b_lo, acc, 0, 0, 0);
    acc = __builtin_amdgcn_mfma_f32_16x16x32_bf16(a_lo, b_hi, acc, 0, 0, 0);
  }

  // epilogue: C/D layout col=lane&15, row=quad*4+reg
  float* outp = part + (size_t)(kb * 3 + mat) * B * F;
  const int f = f0 + l15;
#pragma unroll
  for (int r = 0; r < 4; ++r) {
    int brow = (wave << 4) + (quad << 2) + r;
    outp[brow * F + f] = acc[r];
  }
}

// attended[b,f], prep fused. Grid (B, 4) = 256 blocks = exactly 1/CU.
// Per (b, yblk of 512 f's):
//  1. each thread sums the KSPLIT k/v partials for 2 g's, ballot-compacts
//     active pairs into a 16 KB LDS stream, wave+block reduce kmax/kmin/vsum.
//     Staging duplication per b: 4 blocks x 2 partials (was 8 x 4 = 4x more).
//  2. exp phase: 16 waves own distinct 1/16 slices of the stream; each lane
//     serves 8 fi (r*64+lane) per broadcast quad -> VALU:LDS = 48:1, issue-
//     bound work conserved vs round 5.
//  3. rn/rd[16][512] slice partials; 512-thread final fold.
__global__ __launch_bounds__(1024, 4) void attn_kernel(
    const float* __restrict__ part, const int* __restrict__ mask,
    float* __restrict__ out) {
  __shared__ __align__(16) float kvs[2 * F];   // 16 KB compacted (k,v) stream
  __shared__ float rn[16][512];                // 32 KB slice partials
  __shared__ float rd[16][512];                // 32 KB
  __shared__ float swv[16], swm[16], swn[16];
  __shared__ int scnt;

  const int b    = blockIdx.x;
  const int tid  = threadIdx.x;
  const int wid  = __builtin_amdgcn_readfirstlane(tid >> 6);  // wave-uniform
  const int lane = tid & 63;
  const int fbase = blockIdx.y * 512;

  if (tid == 0) scnt = 0;
  __syncthreads();

  // q prologue: each lane owns 8 fi (r*64+lane)
  float qsum[8];
#pragma unroll
  for (int r = 0; r < 8; ++r) {
    const int fi = fbase + (r << 6) + lane;
    float s = 0.f;
#pragma unroll
    for (int p = 0; p < KSPLIT; ++p) s += part[((p * 3 + 0) * B + b) * F + fi];
    qsum[r] = s;
  }

  // stage+reduce k/v partials for 2 g's, then compact
  const int g0 = tid << 1;
  float2 k2 = {0.f, 0.f}, v2 = {0.f, 0.f};
#pragma unroll
  for (int p = 0; p < KSPLIT; ++p) {
    const float2 kp = *(const float2*)&part[((p * 3 + 1) * B + b) * F + g0];
    const float2 vp = *(const float2*)&part[((p * 3 + 2) * B + b) * F + g0];
    k2.x += kp.x; k2.y += kp.y;
    v2.x += vp.x; v2.y += vp.y;
  }
  float vs = v2.x + v2.y;                       // all v (fallback path)

  const int2 m2 = *(const int2*)&mask[b * F + g0];
  const bool a0 = (m2.x != 0), a1 = (m2.y != 0);
  const unsigned long long bal0 = __ballot(a0);
  const unsigned long long bal1 = __ballot(a1);
  const int tot = __popcll(bal0) + __popcll(bal1);
  int base = 0;
  if (lane == 0) base = atomicAdd(&scnt, tot);
  base = __shfl(base, 0);

  const unsigned long long ltm = (1ull << lane) - 1ull;
  float kmx = -3.4e38f, kmn = 3.4e38f;
  if (a0) {
    int pos = base + __popcll(bal0 & ltm);
    *(float2*)&kvs[2 * pos] = (float2){k2.x, v2.x};
    kmx = fmaxf(kmx, k2.x); kmn = fminf(kmn, k2.x);
  }
  if (a1) {
    int pos = base + __popcll(bal0) + __popcll(bal1 & ltm);
    *(float2*)&kvs[2 * pos] = (float2){k2.y, v2.y};
    kmx = fmaxf(kmx, k2.y); kmn = fminf(kmn, k2.y);
  }

#pragma unroll
  for (int o = 32; o > 0; o >>= 1) {
    vs += __shfl_xor(vs, o);
    kmx = fmaxf(kmx, __shfl_xor(kmx, o));
    kmn = fminf(kmn, __shfl_xor(kmn, o));
  }
  if (lane == 0) { swv[wid] = vs; swm[wid] = kmx; swn[wid] = kmn; }
  __syncthreads();   // compacted stream + reductions visible

  const int ntot = scnt;
  float km = -3.4e38f, kn = 3.4e38f, vstot = 0.f;
#pragma unroll
  for (int w = 0; w < 16; ++w) {
    km = fmaxf(km, swm[w]);
    kn = fminf(kn, swn[w]);
    vstot += swv[w];
  }

  const float L2E = 1.44269504088896f;
  float se[8], nm[8];
#pragma unroll
  for (int r = 0; r < 8; ++r) {
    se[r] = qsum[r] * L2E;
    nm[r] = -se[r] * ((qsum[r] >= 0.f) ? km : kn);
  }

  float n[8] = {0.f, 0.f, 0.f, 0.f, 0.f, 0.f, 0.f, 0.f};
  float d[8] = {0.f, 0.f, 0.f, 0.f, 0.f, 0.f, 0.f, 0.f};
  {
    const int quads = ntot >> 1;               // float4 groups (2 pairs)
    const int q0 = (wid * quads) >> 4;         // this wave's distinct slice
    const int q1 = ((wid + 1) * quads) >> 4;
    const float4* bp = (const float4*)kvs;
    for (int q = q0; q < q1; ++q) {            // broadcast ds_read_b128
      const float4 p = bp[q];
#pragma unroll
      for (int r = 0; r < 8; ++r) {
        float e0 = EXP2(fmaf(se[r], p.x, nm[r]));
        float e1 = EXP2(fmaf(se[r], p.z, nm[r]));
        n[r] = fmaf(e0, p.y, n[r]); d[r] += e0;
        n[r] = fmaf(e1, p.w, n[r]); d[r] += e1;
      }
    }
    if ((wid == 15) && (ntot & 1)) {           // odd tail pair
      const float2 p = *(const float2*)(kvs + 2 * (ntot - 1));
#pragma unroll
      for (int r = 0; r < 8; ++r) {
        float e = EXP2(fmaf(se[r], p.x, nm[r]));
        n[r] = fmaf(e, p.y, n[r]); d[r] += e;
      }
    }
  }
#pragma unroll
  for (int r = 0; r < 8; ++r) {
    rn[wid][(r << 6) + lane] = n[r];
    rd[wid][(r << 6) + lane] = d[r];
  }
  __syncthreads();
  if (tid < 512) {                             // fold 16 slices per fi
    float N = 0.f, D = 0.f;
#pragma unroll
    for (int s = 0; s < 16; ++s) { N += rn[s][tid]; D += rd[s][tid]; }
    out[b * F + fbase + tid] =
        (ntot > 0) ? (N / D) : (vstot * (1.0f / (float)F));
  }
}

extern "C" void kernel_launch(void* const* d_in, const int* in_sizes, int n_in,
                              void* d_out, int out_size, void* d_ws, size_t ws_size,
                              hipStream_t stream) {
  const float* x  = (const float*)d_in[0];
  const int* mask = (const int*)d_in[1];
  const float* Wq = (const float*)d_in[2];
  const float* Wk = (const float*)d_in[3];
  const float* Wv = (const float*)d_in[4];
  float* out = (float*)d_out;

  float* part = (float*)d_ws;                  // 3.1 MB

  dim3 gg(F / BN, KSPLIT, 3);
  qkv_gemm_kernel<<<gg, 256, 0, stream>>>(x, Wq, Wk, Wv, part);
  dim3 ga(B, F / 512);
  attn_kernel<<<ga, 1024, 0, stream>>>(part, mask, out);
}

// Round 7
// 119.809 us; speedup vs baseline: 1.0640x; 1.0640x over previous
//
#include <hip/hip_runtime.h>
#include <hip/hip_bf16.h>

#define B 64
#define F 2048
#define BN 32
#define BK 32
#define KSPLIT 4
#define KCHUNK (F / KSPLIT)   // 512
#define NITER (KCHUNK / BK)   // 16
#define LDSW 40               // LDS row stride in shorts (80 B, 16B-aligned rows)

typedef __attribute__((ext_vector_type(8))) short bf16x8;
typedef __attribute__((ext_vector_type(4))) float f32x4;
typedef __attribute__((ext_vector_type(2))) float f32x2;

#define PART_FLOATS (KSPLIT * 3 * B * F)  // 6.3 MB

#if __has_builtin(__builtin_amdgcn_exp2f)
#define EXP2(x) __builtin_amdgcn_exp2f(x)   // raw v_exp_f32, no denorm expansion
#else
#define EXP2(x) exp2f(x)
#endif

// Packed fp32 VOP3P helpers (compiler never auto-emits these here).
// pk_arg: lo = snm.x*k.x + snm.y ; hi = snm.x*k.y + snm.y
//   (op_sel pulls se from lo word, nm from hi word of the SAME reg pair)
__device__ __forceinline__ f32x2 pk_arg(f32x2 snm, f32x2 k2) {
  f32x2 d;
  asm("v_pk_fma_f32 %0, %1, %2, %1 op_sel:[0,0,1] op_sel_hi:[0,1,1]"
      : "=v"(d) : "v"(snm), "v"(k2));
  return d;
}
__device__ __forceinline__ f32x2 pk_fma(f32x2 a, f32x2 b, f32x2 c) {
  f32x2 d;
  asm("v_pk_fma_f32 %0, %1, %2, %3" : "=v"(d) : "v"(a), "v"(b), "v"(c));
  return d;
}
__device__ __forceinline__ f32x2 pk_add(f32x2 a, f32x2 b) {
  f32x2 d;
  asm("v_pk_add_f32 %0, %1, %2" : "=v"(d) : "v"(a), "v"(b));
  return d;
}

// RTZ hi/lo split of two floats, packed via v_perm. 3 ops/float.
__device__ __forceinline__ void split2(float f0, float f1, int& hi, int& lo) {
  union { float f; unsigned u; } a, b;
  a.f = f0; b.f = f1;
  union { unsigned u; float f; } ha, hb;
  ha.u = a.u & 0xFFFF0000u;
  hb.u = b.u & 0xFFFF0000u;
  union { float f; unsigned u; } la, lb;
  la.f = f0 - ha.f;
  lb.f = f1 - hb.f;
  hi = (int)__builtin_amdgcn_perm(b.u, a.u, 0x07060302u);
  lo = (int)__builtin_amdgcn_perm(lb.u, la.u, 0x07060302u);
}

// C[b,f] = sum_k x[b,k]*W[f,k], bf16 hi/lo split (3 MFMAs ~ fp32 accuracy).
// Split-K partials -> part[(kb*3+mat)*B*F]. LDS double-buffered, 1 barrier/iter.
// BN=32 x KSPLIT=4 -> 768 blocks = 3/CU, float4 (16B/lane) staging loads.
// VERIFIED config (rounds 3-5); round-6's BN=16 float2 staging regressed.
__global__ __launch_bounds__(256) void qkv_gemm_kernel(
    const float* __restrict__ x, const float* __restrict__ Wq,
    const float* __restrict__ Wk, const float* __restrict__ Wv,
    float* __restrict__ part) {
  __shared__ __align__(16) short xs_hi[2][B][LDSW];
  __shared__ __align__(16) short xs_lo[2][B][LDSW];
  __shared__ __align__(16) short ws_hi[2][BN][LDSW];
  __shared__ __align__(16) short ws_lo[2][BN][LDSW];

  const int tid  = threadIdx.x;
  const int f0   = blockIdx.x * BN;
  const int kb   = blockIdx.y;
  const int mat  = blockIdx.z;
  const float* W = (mat == 0) ? Wq : (mat == 1) ? Wk : Wv;

  const int lrow = tid >> 2;           // x staging row 0..63
  const int lc0  = (tid & 3) << 3;     // x staging col (shorts) 0,8,16,24
  const int wrow = tid >> 3;           // W staging row 0..31
  const int wc0  = (tid & 7) << 2;     // W staging col (shorts) 0,4,...,28

  const int wave = tid >> 6;
  const int lane = tid & 63;
  const int l15  = lane & 15;
  const int quad = lane >> 4;

  const float* xg = x + lrow * F + kb * KCHUNK + lc0;
  const float* wg = W + (f0 + wrow) * F + kb * KCHUNK + wc0;

  f32x4 acc[2];
#pragma unroll
  for (int i = 0; i < 2; ++i) acc[i] = (f32x4){0.f, 0.f, 0.f, 0.f};

  float4 px[2][2], pw[2];
  px[0][0] = *(const float4*)(xg);
  px[0][1] = *(const float4*)(xg + 4);
  pw[0]    = *(const float4*)(wg);

#pragma unroll
  for (int it = 0; it < NITER; ++it) {
    const int cur = it & 1, nxt = cur ^ 1;
    if (it + 1 < NITER) {  // prefetch next chunk into alternate regs
      const float* xp = xg + (it + 1) * BK;
      px[nxt][0] = *(const float4*)(xp);
      px[nxt][1] = *(const float4*)(xp + 4);
      pw[nxt]    = *(const float4*)(wg + (it + 1) * BK);
    }
    int4 xh, xl;
    int2 wh, wl;
    split2(px[cur][0].x, px[cur][0].y, xh.x, xl.x);
    split2(px[cur][0].z, px[cur][0].w, xh.y, xl.y);
    split2(px[cur][1].x, px[cur][1].y, xh.z, xl.z);
    split2(px[cur][1].z, px[cur][1].w, xh.w, xl.w);
    split2(pw[cur].x, pw[cur].y, wh.x, wl.x);
    split2(pw[cur].z, pw[cur].w, wh.y, wl.y);
    *(int4*)&xs_hi[cur][lrow][lc0] = xh;
    *(int4*)&xs_lo[cur][lrow][lc0] = xl;
    *(int2*)&ws_hi[cur][wrow][wc0] = wh;
    *(int2*)&ws_lo[cur][wrow][wc0] = wl;
    __syncthreads();  // writes[cur] visible; prior iter's reads drained

    bf16x8 a_hi = *(const bf16x8*)&xs_hi[cur][(wave << 4) + l15][quad << 3];
    bf16x8 a_lo = *(const bf16x8*)&xs_lo[cur][(wave << 4) + l15][quad << 3];
#pragma unroll
    for (int nt = 0; nt < 2; ++nt) {
      bf16x8 b_hi = *(const bf16x8*)&ws_hi[cur][(nt << 4) + l15][quad << 3];
      bf16x8 b_lo = *(const bf16x8*)&ws_lo[cur][(nt << 4) + l15][quad << 3];
      acc[nt] = __builtin_amdgcn_mfma_f32_16x16x32_bf16(a_hi, b_hi, acc[nt], 0, 0, 0);
      acc[nt] = __builtin_amdgcn_mfma_f32_16x16x32_bf16(a_hi, b_lo, acc[nt], 0, 0, 0);
      acc[nt] = __builtin_amdgcn_mfma_f32_16x16x32_bf16(a_lo, b_hi, acc[nt], 0, 0, 0);
    }
  }

  // epilogue: C/D layout col=lane&15, row=quad*4+reg
  float* outp = part + (size_t)(kb * 3 + mat) * B * F;
#pragma unroll
  for (int nt = 0; nt < 2; ++nt) {
    int f = f0 + (nt << 4) + l15;
#pragma unroll
    for (int r = 0; r < 4; ++r) {
      int brow = (wave << 4) + (quad << 2) + r;
      outp[brow * F + f] = acc[nt][r];
    }
  }
}

// attended[b,f], prep fused. Grid (B, 8), 2 blocks/CU (verified occupancy).
// Per (b, yblk of 256 f's):
//  1. each thread sums the KSPLIT k/v partials for 2 g's, ballot-compacts
//     active elements into SPLIT k[]/v[] LDS streams (register-contiguous
//     element pairs for packed math), wave+block reduce kmax/kmin/vsum.
//  2. exp phase, packed-fp32: 16 waves own distinct 1/16 slices; each lane
//     serves 4 fi per broadcast quad. Per 2 elements: 1 v_pk_fma (both exp
//     args via op_sel {se,nm} trick) + 2 v_exp + 1 v_pk_fma (n) + 1 v_pk_add
//     (d) = 1.5 VALU + 1 trans per element (was 3 + 1).
//  3. rn/rd[16][256] slice partials; 256-thread final fold.
__global__ __launch_bounds__(1024, 8) void attn_kernel(
    const float* __restrict__ part, const int* __restrict__ mask,
    float* __restrict__ out) {
  __shared__ __align__(16) float kvs_k[F];     // 8 KB compacted k stream
  __shared__ __align__(16) float kvs_v[F];     // 8 KB compacted v stream
  __shared__ float rn[16][256];                // 16 KB slice partials
  __shared__ float rd[16][256];                // 16 KB
  __shared__ float swv[16], swm[16], swn[16];
  __shared__ int scnt;

  const int b    = blockIdx.x;
  const int tid  = threadIdx.x;
  const int wid  = __builtin_amdgcn_readfirstlane(tid >> 6);  // wave-uniform
  const int lane = tid & 63;

  if (tid == 0) scnt = 0;
  __syncthreads();

  // q prologue: each lane owns 4 fi (r*64+lane)
  float qsum[4];
#pragma unroll
  for (int r = 0; r < 4; ++r) {
    const int fi = blockIdx.y * 256 + (r << 6) + lane;
    float s = 0.f;
#pragma unroll
    for (int p = 0; p < KSPLIT; ++p) s += part[((p * 3 + 0) * B + b) * F + fi];
    qsum[r] = s;
  }

  // stage+reduce k/v partials for 2 g's, then compact (split k/v arrays)
  const int g0 = tid << 1;
  float2 k2 = {0.f, 0.f}, v2 = {0.f, 0.f};
#pragma unroll
  for (int p = 0; p < KSPLIT; ++p) {
    const float2 kp = *(const float2*)&part[((p * 3 + 1) * B + b) * F + g0];
    const float2 vp = *(const float2*)&part[((p * 3 + 2) * B + b) * F + g0];
    k2.x += kp.x; k2.y += kp.y;
    v2.x += vp.x; v2.y += vp.y;
  }
  float vs = v2.x + v2.y;                       // all v (fallback path)

  const int2 m2 = *(const int2*)&mask[b * F + g0];
  const bool a0 = (m2.x != 0), a1 = (m2.y != 0);
  const unsigned long long bal0 = __ballot(a0);
  const unsigned long long bal1 = __ballot(a1);
  const int tot = __popcll(bal0) + __popcll(bal1);
  int base = 0;
  if (lane == 0) base = atomicAdd(&scnt, tot);
  base = __shfl(base, 0);

  const unsigned long long ltm = (1ull << lane) - 1ull;
  float kmx = -3.4e38f, kmn = 3.4e38f;
  if (a0) {
    int pos = base + __popcll(bal0 & ltm);
    kvs_k[pos] = k2.x; kvs_v[pos] = v2.x;
    kmx = fmaxf(kmx, k2.x); kmn = fminf(kmn, k2.x);
  }
  if (a1) {
    int pos = base + __popcll(bal0) + __popcll(bal1 & ltm);
    kvs_k[pos] = k2.y; kvs_v[pos] = v2.y;
    kmx = fmaxf(kmx, k2.y); kmn = fminf(kmn, k2.y);
  }

#pragma unroll
  for (int o = 32; o > 0; o >>= 1) {
    vs += __shfl_xor(vs, o);
    kmx = fmaxf(kmx, __shfl_xor(kmx, o));
    kmn = fminf(kmn, __shfl_xor(kmn, o));
  }
  if (lane == 0) { swv[wid] = vs; swm[wid] = kmx; swn[wid] = kmn; }
  __syncthreads();   // compacted streams + reductions visible

  const int ntot = scnt;
  float km = -3.4e38f, kn = 3.4e38f, vstot = 0.f;
#pragma unroll
  for (int w = 0; w < 16; ++w) {
    km = fmaxf(km, swm[w]);
    kn = fminf(kn, swn[w]);
    vstot += swv[w];
  }

  const float L2E = 1.44269504088896f;
  f32x2 snm[4];                                 // {se, nm} per fi
#pragma unroll
  for (int r = 0; r < 4; ++r) {
    const float se = qsum[r] * L2E;
    snm[r] = (f32x2){se, -se * ((qsum[r] >= 0.f) ? km : kn)};
  }

  f32x2 n2[4], d2[4];
#pragma unroll
  for (int r = 0; r < 4; ++r) {
    n2[r] = (f32x2){0.f, 0.f};
    d2[r] = (f32x2){0.f, 0.f};
  }
  {
    const int nq = ntot >> 2;                  // groups of 4 elements
    const int q0 = (wid * nq) >> 4;            // this wave's distinct slice
    const int q1 = ((wid + 1) * nq) >> 4;
    const float4* kp4 = (const float4*)kvs_k;
    const float4* vp4 = (const float4*)kvs_v;
    for (int q = q0; q < q1; ++q) {            // 2x broadcast ds_read_b128
      const float4 k4 = kp4[q];
      const float4 v4 = vp4[q];
      const f32x2 ka = {k4.x, k4.y}, kb = {k4.z, k4.w};
      const f32x2 va = {v4.x, v4.y}, vb = {v4.z, v4.w};
#pragma unroll
      for (int r = 0; r < 4; ++r) {
        const f32x2 aa = pk_arg(snm[r], ka);
        const f32x2 ab = pk_arg(snm[r], kb);
        const f32x2 ea = {EXP2(aa.x), EXP2(aa.y)};
        const f32x2 eb = {EXP2(ab.x), EXP2(ab.y)};
        n2[r] = pk_fma(ea, va, n2[r]);
        n2[r] = pk_fma(eb, vb, n2[r]);
        d2[r] = pk_add(ea, d2[r]);
        d2[r] = pk_add(eb, d2[r]);
      }
    }
    if (wid == 15) {                           // tail 0..3 elements
      for (int e = nq << 2; e < ntot; ++e) {
        const float kk = kvs_k[e], vv = kvs_v[e];
#pragma unroll
        for (int r = 0; r < 4; ++r) {
          const float ee = EXP2(fmaf(snm[r].x, kk, snm[r].y));
          n2[r].x = fmaf(ee, vv, n2[r].x);
          d2[r].x += ee;
        }
      }
    }
  }
#pragma unroll
  for (int r = 0; r < 4; ++r) {
    rn[wid][(r << 6) + lane] = n2[r].x + n2[r].y;
    rd[wid][(r << 6) + lane] = d2[r].x + d2[r].y;
  }
  __syncthreads();
  if (tid < 256) {                             // fold 16 slices per fi
    float N = 0.f, D = 0.f;
#pragma unroll
    for (int s = 0; s < 16; ++s) { N += rn[s][tid]; D += rd[s][tid]; }
    out[b * F + blockIdx.y * 256 + tid] =
        (ntot > 0) ? (N / D) : (vstot * (1.0f / (float)F));
  }
}

extern "C" void kernel_launch(void* const* d_in, const int* in_sizes, int n_in,
                              void* d_out, int out_size, void* d_ws, size_t ws_size,
                              hipStream_t stream) {
  const float* x  = (const float*)d_in[0];
  const int* mask = (const int*)d_in[1];
  const float* Wq = (const float*)d_in[2];
  const float* Wk = (const float*)d_in[3];
  const float* Wv = (const float*)d_in[4];
  float* out = (float*)d_out;

  float* part = (float*)d_ws;                  // 6.3 MB

  dim3 gg(F / BN, KSPLIT, 3);
  qkv_gemm_kernel<<<gg, 256, 0, stream>>>(x, Wq, Wk, Wv, part);
  dim3 ga(B, F / 256);
  attn_kernel<<<ga, 1024, 0, stream>>>(part, mask, out);
}